// Round 1
// baseline (9172.887 us; speedup 1.0000x reference)
//
#include <hip/hip_runtime.h>
#include <math.h>

#define BDIM 2
#define SLEN 2048
#define DMODEL 2048
#define NH 16
#define NKV 4
#define HD 128

// ---------------------------------------------------------------------------
// f32 tiled GEMM: C[M,N] = A[M,K] @ B[K,N]. 64x64 tile, BK=16, 256 threads,
// 4x4 micro-tile per thread. LDS pads chosen so compute reads are
// broadcast (A) or 2-way (B) => free per m136.
// ---------------------------------------------------------------------------
__global__ __launch_bounds__(256) void gemm64_f32(
    const float* __restrict__ A, const float* __restrict__ B,
    float* __restrict__ C, int M, int N, int K) {
  __shared__ float As[16][65];  // [k][m], transposed
  __shared__ float Bs[16][65];  // [k][n]
  const int t  = threadIdx.x;
  const int tx = t & 15, ty = t >> 4;
  const int bm = blockIdx.y * 64, bn = blockIdx.x * 64;

  const int arow = t >> 2, aquad = t & 3;     // A tile: 64 rows x 16 k
  const int bkk  = t >> 4, bn4   = (t & 15) * 4;  // B tile: 16 k x 64 n

  float acc[4][4] = {};

  for (int k0 = 0; k0 < K; k0 += 16) {
    float4 a4 = *reinterpret_cast<const float4*>(
        &A[(size_t)(bm + arow) * K + k0 + aquad * 4]);
    float4 b4 = *reinterpret_cast<const float4*>(
        &B[(size_t)(k0 + bkk) * N + bn + bn4]);
    As[aquad * 4 + 0][arow] = a4.x;
    As[aquad * 4 + 1][arow] = a4.y;
    As[aquad * 4 + 2][arow] = a4.z;
    As[aquad * 4 + 3][arow] = a4.w;
    Bs[bkk][bn4 + 0] = b4.x;
    Bs[bkk][bn4 + 1] = b4.y;
    Bs[bkk][bn4 + 2] = b4.z;
    Bs[bkk][bn4 + 3] = b4.w;
    __syncthreads();
#pragma unroll
    for (int kk = 0; kk < 16; ++kk) {
      float a[4], b[4];
#pragma unroll
      for (int i = 0; i < 4; ++i) a[i] = As[kk][ty * 4 + i];
#pragma unroll
      for (int j = 0; j < 4; ++j) b[j] = Bs[kk][tx * 4 + j];
#pragma unroll
      for (int i = 0; i < 4; ++i)
#pragma unroll
        for (int j = 0; j < 4; ++j) acc[i][j] = fmaf(a[i], b[j], acc[i][j]);
    }
    __syncthreads();
  }

#pragma unroll
  for (int i = 0; i < 4; ++i) {
    float4 o = make_float4(acc[i][0], acc[i][1], acc[i][2], acc[i][3]);
    *reinterpret_cast<float4*>(&C[(size_t)(bm + ty * 4 + i) * N + bn + tx * 4]) = o;
  }
}

// ---------------------------------------------------------------------------
// RoPE + xPos scaling, in place on a (B*S, nheads*128) f32 buffer.
// Thread handles the rotation pair (dp, dp+64); both have the same parity, so
// the same xPos even/odd factor applies to both outputs.
// invert=0 -> q (scale even, 1/scale odd); invert=1 -> k (reciprocal).
// ---------------------------------------------------------------------------
__global__ __launch_bounds__(256) void rope_xpos_k(
    float* __restrict__ buf, int nh_shift, int invert) {
  const int idx = blockIdx.x * 256 + threadIdx.x;
  const int dp  = idx & 63;
  const int tmp = idx >> 6;
  const int h   = tmp & ((1 << nh_shift) - 1);
  const int row = tmp >> nh_shift;       // row in [0, B*S)
  const int s   = row & (SLEN - 1);

  // inv_freq = 10000^(-dp/64) ; log(10000) = 9.210340371976184
  const float inv_freq = expf(-(float)dp * (9.210340371976184f / 64.0f));
  const float ang = (float)s * inv_freq;
  float sn, cs;
  sincosf(ang, &sn, &cs);

  float* p = buf + ((size_t)row << (nh_shift + 7)) + ((size_t)h << 7);
  const float x0 = p[dp];
  const float x1 = p[dp + 64];
  float y0 = x0 * cs - x1 * sn;
  float y1 = x1 * cs + x0 * sn;

  const float scl = ((float)s + 256.0f) / 512.0f;
  const float se_even = invert ? (1.0f / scl) : scl;
  const float se_odd  = invert ? scl : (1.0f / scl);
  const float se = (dp & 1) ? se_odd : se_even;

  p[dp]      = y0 * se;
  p[dp + 64] = y1 * se;
}

// ---------------------------------------------------------------------------
// Causal flash attention, f32. One 256-thread block per (b, h, 64-row q tile).
// Online softmax (running max in -1e30 convention; masked = -1e30 so no
// inf-inf NaN). Each thread owns row r = t&63 and a 32-wide d-slice
// (blk = t>>6) of the O accumulator, plus a 16-col slice of the score tile.
// ---------------------------------------------------------------------------
__global__ __launch_bounds__(256) void flash_attn_f32(
    const float* __restrict__ q, const float* __restrict__ k,
    const float* __restrict__ v, float* __restrict__ o) {
  const int bid = blockIdx.x;
  const int qt  = bid & 31;          // q tile (S/64 = 32)
  const int bh  = bid >> 5;
  const int h   = bh & (NH - 1);
  const int b   = bh >> 4;
  const int kvh = h >> 2;            // GQA: kv head = h / 4

  __shared__ float Qs[64][129];
  __shared__ float Ks[64][129];
  __shared__ float Vs[64][129];
  __shared__ float Ps[64][65];
  __shared__ float red[4][64];
  __shared__ float m_s[64], l_s[64], f_s[64];

  const int t   = threadIdx.x;
  const int r   = t & 63;
  const int blk = t >> 6;

  // stage Q tile
  for (int idx = t; idx < 64 * 128; idx += 256) {
    int rr = idx >> 7, d = idx & 127;
    Qs[rr][d] = q[((size_t)(b * SLEN + qt * 64 + rr) * NH + h) * HD + d];
  }
  if (t < 64) { m_s[t] = -1e30f; l_s[t] = 0.0f; }

  float acc[32];
#pragma unroll
  for (int j = 0; j < 32; ++j) acc[j] = 0.0f;

  const float scale = 0.088388347648318447f;  // 1/sqrt(128)

  for (int kt = 0; kt <= qt; ++kt) {
    __syncthreads();
    for (int idx = t; idx < 64 * 128; idx += 256) {
      int rr = idx >> 7, d = idx & 127;
      size_t base = ((size_t)(b * SLEN + kt * 64 + rr) * NKV + kvh) * HD + d;
      Ks[rr][d] = k[base];
      Vs[rr][d] = v[base];
    }
    __syncthreads();

    // ---- scores: thread computes 16 cols (blk*16..+15) of row r
    float sreg[16];
#pragma unroll
    for (int ci = 0; ci < 16; ++ci) sreg[ci] = 0.0f;
#pragma unroll
    for (int dc = 0; dc < 8; ++dc) {
      float qreg[16];
#pragma unroll
      for (int i = 0; i < 16; ++i) qreg[i] = Qs[r][dc * 16 + i];
#pragma unroll
      for (int ci = 0; ci < 16; ++ci) {
        const int c = blk * 16 + ci;
        float ssum = 0.0f;
#pragma unroll
        for (int i = 0; i < 16; ++i) ssum = fmaf(qreg[i], Ks[c][dc * 16 + i], ssum);
        sreg[ci] += ssum;
      }
    }
    float pmax = -1e30f;
#pragma unroll
    for (int ci = 0; ci < 16; ++ci) {
      const int c = blk * 16 + ci;
      float sv = sreg[ci] * scale;
      if (kt == qt && c > r) sv = -1e30f;   // causal mask
      sreg[ci] = sv;
      pmax = fmaxf(pmax, sv);
    }
    red[blk][r] = pmax;
    __syncthreads();
    if (t < 64) {
      float tm = fmaxf(fmaxf(red[0][t], red[1][t]), fmaxf(red[2][t], red[3][t]));
      float m_old = m_s[t];
      float m_new = fmaxf(m_old, tm);
      float f = expf(m_old - m_new);   // m_old=-1e30 first iter -> f = 0
      m_s[t] = m_new;
      f_s[t] = f;
      l_s[t] *= f;
    }
    __syncthreads();
    const float m_new = m_s[r];
    float psum = 0.0f;
#pragma unroll
    for (int ci = 0; ci < 16; ++ci) {
      const int c = blk * 16 + ci;
      float pv = expf(sreg[ci] - m_new);
      Ps[r][c] = pv;
      psum += pv;
    }
    red[blk][r] = psum;
    __syncthreads();
    if (t < 64) l_s[t] += red[0][t] + red[1][t] + red[2][t] + red[3][t];

    // ---- rescale + accumulate O (thread: row r, d-slice blk*32..+31)
    const float f = f_s[r];
#pragma unroll
    for (int j = 0; j < 32; ++j) acc[j] *= f;
    for (int c = 0; c < 64; ++c) {
      const float pv = Ps[r][c];
#pragma unroll
      for (int j = 0; j < 32; ++j) acc[j] = fmaf(pv, Vs[c][blk * 32 + j], acc[j]);
    }
  }

  __syncthreads();
  const float linv = 1.0f / l_s[r];
  float4* op4 = reinterpret_cast<float4*>(
      o + ((size_t)(b * SLEN + qt * 64 + r) * NH + h) * HD + blk * 32);
#pragma unroll
  for (int j = 0; j < 8; ++j) {
    op4[j] = make_float4(acc[j * 4 + 0] * linv, acc[j * 4 + 1] * linv,
                         acc[j * 4 + 2] * linv, acc[j * 4 + 3] * linv);
  }
}

// ---------------------------------------------------------------------------
extern "C" void kernel_launch(void* const* d_in, const int* in_sizes, int n_in,
                              void* d_out, int out_size, void* d_ws, size_t ws_size,
                              hipStream_t stream) {
  (void)in_sizes; (void)n_in; (void)out_size; (void)ws_size;
  const float* x  = (const float*)d_in[0];
  const float* Wq = (const float*)d_in[1];
  const float* Wk = (const float*)d_in[2];
  const float* Wv = (const float*)d_in[3];
  const float* Wo = (const float*)d_in[4];
  float* out = (float*)d_out;

  float* qbuf = (float*)d_ws;                          // 4096 x 2048
  float* kbuf = qbuf + (size_t)4096 * 2048;            // 4096 x 512
  float* vbuf = kbuf + (size_t)4096 * 512;             // 4096 x 512
  float* attn = vbuf + (size_t)4096 * 512;             // 4096 x 2048

  const int M = BDIM * SLEN;  // 4096
  dim3 blk(256);

  // QKV projections
  gemm64_f32<<<dim3(2048 / 64, M / 64), blk, 0, stream>>>(x, Wq, qbuf, M, 2048, 2048);
  gemm64_f32<<<dim3(512 / 64,  M / 64), blk, 0, stream>>>(x, Wk, kbuf, M, 512, 2048);
  gemm64_f32<<<dim3(512 / 64,  M / 64), blk, 0, stream>>>(x, Wv, vbuf, M, 512, 2048);

  // RoPE + xPos (in place)
  rope_xpos_k<<<(M * NH * 64) / 256, blk, 0, stream>>>(qbuf, 4, 0);
  rope_xpos_k<<<(M * NKV * 64) / 256, blk, 0, stream>>>(kbuf, 2, 1);

  // causal GQA flash attention
  flash_attn_f32<<<BDIM * NH * (SLEN / 64), blk, 0, stream>>>(qbuf, kbuf, vbuf, attn);

  // output projection
  gemm64_f32<<<dim3(2048 / 64, M / 64), blk, 0, stream>>>(attn, Wo, out, M, 2048, 2048);
}

// Round 2
// 1919.626 us; speedup vs baseline: 4.7785x; 4.7785x over previous
//
#include <hip/hip_runtime.h>
#include <math.h>

#define BDIM 2
#define SLEN 2048
#define NH 16
#define NKV 4
#define HD 128

typedef __attribute__((ext_vector_type(8))) short short8v;
typedef __attribute__((ext_vector_type(8))) __bf16 bf16x8;
typedef __attribute__((ext_vector_type(4))) float f32x4;

__device__ inline unsigned short f2bf(float x) {
  unsigned int u = __builtin_bit_cast(unsigned int, x);
  unsigned int r = (u + 0x7fffu + ((u >> 16) & 1u)) >> 16;
  return (unsigned short)r;
}

// ---------------------------------------------------------------------------
// f32 tiled GEMM (unchanged from R0): C[M,N] = A[M,K] @ B[K,N].
// ---------------------------------------------------------------------------
__global__ __launch_bounds__(256) void gemm64_f32(
    const float* __restrict__ A, const float* __restrict__ B,
    float* __restrict__ C, int M, int N, int K) {
  __shared__ float As[16][65];
  __shared__ float Bs[16][65];
  const int t  = threadIdx.x;
  const int tx = t & 15, ty = t >> 4;
  const int bm = blockIdx.y * 64, bn = blockIdx.x * 64;
  const int arow = t >> 2, aquad = t & 3;
  const int bkk  = t >> 4, bn4   = (t & 15) * 4;
  float acc[4][4] = {};
  for (int k0 = 0; k0 < K; k0 += 16) {
    float4 a4 = *reinterpret_cast<const float4*>(
        &A[(size_t)(bm + arow) * K + k0 + aquad * 4]);
    float4 b4 = *reinterpret_cast<const float4*>(
        &B[(size_t)(k0 + bkk) * N + bn + bn4]);
    As[aquad * 4 + 0][arow] = a4.x;
    As[aquad * 4 + 1][arow] = a4.y;
    As[aquad * 4 + 2][arow] = a4.z;
    As[aquad * 4 + 3][arow] = a4.w;
    Bs[bkk][bn4 + 0] = b4.x;
    Bs[bkk][bn4 + 1] = b4.y;
    Bs[bkk][bn4 + 2] = b4.z;
    Bs[bkk][bn4 + 3] = b4.w;
    __syncthreads();
#pragma unroll
    for (int kk = 0; kk < 16; ++kk) {
      float a[4], b[4];
#pragma unroll
      for (int i = 0; i < 4; ++i) a[i] = As[kk][ty * 4 + i];
#pragma unroll
      for (int j = 0; j < 4; ++j) b[j] = Bs[kk][tx * 4 + j];
#pragma unroll
      for (int i = 0; i < 4; ++i)
#pragma unroll
        for (int j = 0; j < 4; ++j) acc[i][j] = fmaf(a[i], b[j], acc[i][j]);
    }
    __syncthreads();
  }
#pragma unroll
  for (int i = 0; i < 4; ++i) {
    float4 o = make_float4(acc[i][0], acc[i][1], acc[i][2], acc[i][3]);
    *reinterpret_cast<float4*>(&C[(size_t)(bm + ty * 4 + i) * N + bn + tx * 4]) = o;
  }
}

// ---------------------------------------------------------------------------
// RoPE + xPos; reads f32 proj output, writes bf16. extra_scale folds the
// 1/sqrt(128) attention scale into q. invert=1 for k (reciprocal xpos).
// ---------------------------------------------------------------------------
__global__ __launch_bounds__(256) void rope_xpos_bf16(
    const float* __restrict__ in, unsigned short* __restrict__ outb,
    int nh_shift, int invert, float extra_scale) {
  const int idx = blockIdx.x * 256 + threadIdx.x;
  const int dp  = idx & 63;
  const int tmp = idx >> 6;
  const int h   = tmp & ((1 << nh_shift) - 1);
  const int row = tmp >> nh_shift;
  const int s   = row & (SLEN - 1);

  const float inv_freq = expf(-(float)dp * (9.210340371976184f / 64.0f));
  const float ang = (float)s * inv_freq;
  float sn, cs;
  sincosf(ang, &sn, &cs);

  const size_t base = ((size_t)row << (nh_shift + 7)) + ((size_t)h << 7);
  const float x0 = in[base + dp];
  const float x1 = in[base + dp + 64];
  float y0 = x0 * cs - x1 * sn;
  float y1 = x1 * cs + x0 * sn;

  const float scl = ((float)s + 256.0f) / 512.0f;
  float se_even = invert ? (1.0f / scl) : scl;
  float se_odd  = invert ? scl : (1.0f / scl);
  float se = ((dp & 1) ? se_odd : se_even) * extra_scale;

  outb[base + dp]      = f2bf(y0 * se);
  outb[base + dp + 64] = f2bf(y1 * se);
}

__global__ __launch_bounds__(256) void cast_f32_bf16(
    const float* __restrict__ in, unsigned short* __restrict__ out) {
  const int i = (blockIdx.x * 256 + threadIdx.x) * 8;
  float4 a = *reinterpret_cast<const float4*>(&in[i]);
  float4 b = *reinterpret_cast<const float4*>(&in[i + 4]);
  short8v s;
  s[0] = f2bf(a.x); s[1] = f2bf(a.y); s[2] = f2bf(a.z); s[3] = f2bf(a.w);
  s[4] = f2bf(b.x); s[5] = f2bf(b.y); s[6] = f2bf(b.z); s[7] = f2bf(b.w);
  *reinterpret_cast<short8v*>(&out[i]) = s;
}

// ---------------------------------------------------------------------------
// MFMA flash attention (bf16 in, f32 softmax/accum).
// Block = 256 thr (4 waves), 64 q-rows/block, wave owns 16 q-rows.
// KV tile = 64. Layouts (bank-conflict-checked):
//   Ks/Qs: [64][136] bf16 (pitch 272B) — frag reads ds_read_b128 uniform banks
//   Vt:    [128][72] bf16 (transposed) — PV B-frags contiguous b128
//   Ps:    per-wave [16][72] bf16
// MFMA 16x16x32: A lane(l) slot j -> A[l&15][(l>>4)*8+j];
//                B lane(l) slot j -> B[(l>>4)*8+j][l&15];
//                D lane(l) reg  j -> D[(l>>4)*4+j][l&15]  (verified m89)
// ---------------------------------------------------------------------------
__global__ __launch_bounds__(256) void flash_attn_mfma(
    const unsigned short* __restrict__ qb, const unsigned short* __restrict__ kb,
    const unsigned short* __restrict__ vb, float* __restrict__ o) {
  const int bid = blockIdx.x;
  const int qt  = bid & 31;
  const int bh  = bid >> 5;
  const int h   = bh & (NH - 1);
  const int b   = bh >> 4;
  const int kvh = h >> 2;

  __shared__ __align__(16) unsigned char smem[53248];
  unsigned short* Ks = (unsigned short*)(smem);            // 64*136
  unsigned short* Vt = (unsigned short*)(smem + 17408);    // 128*72
  unsigned short* Qs = (unsigned short*)(smem + 35840);    // 64*136 (reused as Ps)
  unsigned short* Ps = Qs;                                 // 4 waves * 16*72

  const int t    = threadIdx.x;
  const int lane = t & 63;
  const int w    = t >> 6;
  const int lg   = lane >> 4;
  const int l15  = lane & 15;

  // ---- stage Q tile
  for (int idx = t; idx < 64 * 16; idx += 256) {
    int r = idx >> 4, c8 = idx & 15;
    short8v qv = *reinterpret_cast<const short8v*>(
        &qb[((size_t)(b * SLEN + qt * 64 + r) * NH + h) * HD + c8 * 8]);
    *reinterpret_cast<short8v*>(&Qs[r * 136 + c8 * 8]) = qv;
  }
  __syncthreads();

  // ---- Q fragments into registers (wave's 16-row band)
  bf16x8 qfrag[4];
  {
    const unsigned short* qrow = &Qs[(w * 16 + l15) * 136];
#pragma unroll
    for (int kc = 0; kc < 4; ++kc)
      qfrag[kc] = __builtin_bit_cast(bf16x8,
          *reinterpret_cast<const short8v*>(&qrow[kc * 32 + lg * 8]));
  }

  f32x4 Oacc[8];
#pragma unroll
  for (int dt = 0; dt < 8; ++dt) Oacc[dt] = (f32x4){0.f, 0.f, 0.f, 0.f};
  float m_run[4] = {-1e30f, -1e30f, -1e30f, -1e30f};
  float l_run[4] = {0.f, 0.f, 0.f, 0.f};

  for (int kt = 0; kt <= qt; ++kt) {
    __syncthreads();  // previous tile's LDS reads done (also covers Q-frag reads)
    // stage K
    for (int idx = t; idx < 64 * 16; idx += 256) {
      int r = idx >> 4, c8 = idx & 15;
      short8v kv = *reinterpret_cast<const short8v*>(
          &kb[((size_t)(b * SLEN + kt * 64 + r) * NKV + kvh) * HD + c8 * 8]);
      *reinterpret_cast<short8v*>(&Ks[r * 136 + c8 * 8]) = kv;
    }
    // stage V transposed
    for (int idx = t; idx < 64 * 16; idx += 256) {
      int r = idx & 63, c8 = idx >> 6;
      short8v vv = *reinterpret_cast<const short8v*>(
          &vb[((size_t)(b * SLEN + kt * 64 + r) * NKV + kvh) * HD + c8 * 8]);
#pragma unroll
      for (int j = 0; j < 8; ++j) Vt[(c8 * 8 + j) * 72 + r] = (unsigned short)vv[j];
    }
    __syncthreads();

    // ---- QK^T (scale pre-folded into q)
    f32x4 S[4];
#pragma unroll
    for (int ct = 0; ct < 4; ++ct) {
      f32x4 acc = (f32x4){0.f, 0.f, 0.f, 0.f};
      const unsigned short* krow = &Ks[(ct * 16 + l15) * 136];
#pragma unroll
      for (int kc = 0; kc < 4; ++kc) {
        bf16x8 kf = __builtin_bit_cast(bf16x8,
            *reinterpret_cast<const short8v*>(&krow[kc * 32 + lg * 8]));
        acc = __builtin_amdgcn_mfma_f32_16x16x32_bf16(qfrag[kc], kf, acc, 0, 0, 0);
      }
      S[ct] = acc;
    }
    // ---- causal mask (only diagonal tile)
    if (kt == qt) {
#pragma unroll
      for (int ct = 0; ct < 4; ++ct) {
        int col = ct * 16 + l15;
#pragma unroll
        for (int j = 0; j < 4; ++j) {
          int row = w * 16 + lg * 4 + j;
          if (col > row) S[ct][j] = -1e30f;
        }
      }
    }
    // ---- online softmax (per row j; stats across 16-lane group)
    float f_j[4];
#pragma unroll
    for (int j = 0; j < 4; ++j) {
      float mx = fmaxf(fmaxf(S[0][j], S[1][j]), fmaxf(S[2][j], S[3][j]));
      mx = fmaxf(mx, __shfl_xor(mx, 1));
      mx = fmaxf(mx, __shfl_xor(mx, 2));
      mx = fmaxf(mx, __shfl_xor(mx, 4));
      mx = fmaxf(mx, __shfl_xor(mx, 8));
      float m_new = fmaxf(m_run[j], mx);
      float f = __expf(m_run[j] - m_new);
      m_run[j] = m_new;
      f_j[j] = f;
      float ps = 0.f;
#pragma unroll
      for (int ct = 0; ct < 4; ++ct) {
        float pv = __expf(S[ct][j] - m_new);
        ps += pv;
        Ps[w * 1152 + (lg * 4 + j) * 72 + ct * 16 + l15] = f2bf(pv);
      }
      ps += __shfl_xor(ps, 1);
      ps += __shfl_xor(ps, 2);
      ps += __shfl_xor(ps, 4);
      ps += __shfl_xor(ps, 8);
      l_run[j] = l_run[j] * f + ps;
    }
    __syncthreads();  // P visible (and drains own-wave ds_writes)

    // ---- rescale O, then PV accumulate
#pragma unroll
    for (int dt = 0; dt < 8; ++dt) {
#pragma unroll
      for (int j = 0; j < 4; ++j) Oacc[dt][j] *= f_j[j];
    }
    const unsigned short* prow = &Ps[w * 1152 + l15 * 72];
#pragma unroll
    for (int kc = 0; kc < 2; ++kc) {
      bf16x8 pf = __builtin_bit_cast(bf16x8,
          *reinterpret_cast<const short8v*>(&prow[kc * 32 + lg * 8]));
#pragma unroll
      for (int dt = 0; dt < 8; ++dt) {
        bf16x8 vf = __builtin_bit_cast(bf16x8,
            *reinterpret_cast<const short8v*>(&Vt[(dt * 16 + l15) * 72 + kc * 32 + lg * 8]));
        Oacc[dt] = __builtin_amdgcn_mfma_f32_16x16x32_bf16(pf, vf, Oacc[dt], 0, 0, 0);
      }
    }
  }

  // ---- normalize + write (f32, attn layout [row][h*128+d])
  float linv[4];
#pragma unroll
  for (int j = 0; j < 4; ++j) linv[j] = 1.0f / l_run[j];
#pragma unroll
  for (int dt = 0; dt < 8; ++dt) {
#pragma unroll
    for (int j = 0; j < 4; ++j) {
      size_t row = (size_t)(b * SLEN + qt * 64 + w * 16 + lg * 4 + j);
      o[row * 2048 + h * HD + dt * 16 + l15] = Oacc[dt][j] * linv[j];
    }
  }
}

// ---------------------------------------------------------------------------
extern "C" void kernel_launch(void* const* d_in, const int* in_sizes, int n_in,
                              void* d_out, int out_size, void* d_ws, size_t ws_size,
                              hipStream_t stream) {
  (void)in_sizes; (void)n_in; (void)out_size; (void)ws_size;
  const float* x  = (const float*)d_in[0];
  const float* Wq = (const float*)d_in[1];
  const float* Wk = (const float*)d_in[2];
  const float* Wv = (const float*)d_in[3];
  const float* Wo = (const float*)d_in[4];
  float* out = (float*)d_out;

  float* qbuf = (float*)d_ws;                              // 4096x2048 f32
  float* kbuf = qbuf + (size_t)4096 * 2048;                // 4096x512  f32
  float* vbuf = kbuf + (size_t)4096 * 512;                 // 4096x512  f32
  unsigned short* qb = (unsigned short*)(vbuf + (size_t)4096 * 512);  // bf16
  unsigned short* kb = qb + (size_t)4096 * 2048;
  unsigned short* vb = kb + (size_t)4096 * 512;
  float* attn = qbuf;  // alias: qbuf f32 dead once qb is built

  const int M = BDIM * SLEN;  // 4096
  dim3 blk(256);

  gemm64_f32<<<dim3(2048 / 64, M / 64), blk, 0, stream>>>(x, Wq, qbuf, M, 2048, 2048);
  gemm64_f32<<<dim3(512 / 64,  M / 64), blk, 0, stream>>>(x, Wk, kbuf, M, 512, 2048);
  gemm64_f32<<<dim3(512 / 64,  M / 64), blk, 0, stream>>>(x, Wv, vbuf, M, 512, 2048);

  rope_xpos_bf16<<<(M * NH * 64) / 256, blk, 0, stream>>>(
      qbuf, qb, 4, 0, 0.088388347648318447f);
  rope_xpos_bf16<<<(M * NKV * 64) / 256, blk, 0, stream>>>(kbuf, kb, 2, 1, 1.0f);
  cast_f32_bf16<<<(M * 512) / (256 * 8), blk, 0, stream>>>(vbuf, vb);

  flash_attn_mfma<<<BDIM * NH * (SLEN / 64), blk, 0, stream>>>(qb, kb, vb, attn);

  gemm64_f32<<<dim3(2048 / 64, M / 64), blk, 0, stream>>>(attn, Wo, out, M, 2048, 2048);
}

// Round 3
// 473.988 us; speedup vs baseline: 19.3526x; 4.0499x over previous
//
#include <hip/hip_runtime.h>
#include <math.h>

#define BDIM 2
#define SLEN 2048
#define NH 16
#define NKV 4
#define HD 128

typedef __attribute__((ext_vector_type(8))) short short8v;
typedef __attribute__((ext_vector_type(8))) __bf16 bf16x8;
typedef __attribute__((ext_vector_type(4))) float f32x4;

__device__ inline unsigned short f2bf(float x) {
  unsigned int u = __builtin_bit_cast(unsigned int, x);
  unsigned int r = (u + 0x7fffu + ((u >> 16) & 1u)) >> 16;
  return (unsigned short)r;
}
__device__ inline float bf2f(unsigned short b) {
  unsigned int u = ((unsigned int)b) << 16;
  return __builtin_bit_cast(float, u);
}

// ---------------------------------------------------------------------------
// bf16 MFMA GEMM, m97 structure: C[M,N] = A[M,K] @ Bt[N,K]^T.
// 128x128 tile, BK=64, 256 thr (4 waves 2x2), global_load_lds width 16,
// linear LDS [128][64] bf16, 2 barriers per K-step. f32 accum.
// ---------------------------------------------------------------------------
template <bool BF16_OUT>
__global__ __launch_bounds__(256) void gemm_mfma_bt(
    const unsigned short* __restrict__ A,   // [M][K] bf16
    const unsigned short* __restrict__ Bt,  // [N][K] bf16
    void* __restrict__ C,                   // [M][N]
    int M, int N, int K) {
  __shared__ __align__(16) unsigned short As[128 * 64];
  __shared__ __align__(16) unsigned short Bs[128 * 64];
  const int t    = threadIdx.x;
  const int lane = t & 63;
  const int w    = t >> 6;
  const int lg   = lane >> 4, l15 = lane & 15;
  const int wr   = w >> 1,    wc  = w & 1;
  const int bm = blockIdx.y * 128, bn = blockIdx.x * 128;

  // staging: wave w covers rows w*32 + i*8 + (lane>>3), k-cols (lane&7)*8
  const int srow = w * 32 + (lane >> 3);
  const int scol = (lane & 7) * 8;
  const unsigned short* gA = &A[(size_t)(bm + srow) * K + scol];
  const unsigned short* gB = &Bt[(size_t)(bn + srow) * K + scol];

  f32x4 acc[4][4];
#pragma unroll
  for (int m = 0; m < 4; ++m)
#pragma unroll
    for (int n = 0; n < 4; ++n) acc[m][n] = (f32x4){0.f, 0.f, 0.f, 0.f};

  for (int k0 = 0; k0 < K; k0 += 64) {
    __syncthreads();  // previous tile's LDS reads complete
#pragma unroll
    for (int i = 0; i < 4; ++i) {
      __builtin_amdgcn_global_load_lds(
          (const __attribute__((address_space(1))) unsigned int*)(gA + (size_t)i * 8 * K + k0),
          (__attribute__((address_space(3))) unsigned int*)&As[(w * 32 + i * 8) * 64],
          16, 0, 0);
      __builtin_amdgcn_global_load_lds(
          (const __attribute__((address_space(1))) unsigned int*)(gB + (size_t)i * 8 * K + k0),
          (__attribute__((address_space(3))) unsigned int*)&Bs[(w * 32 + i * 8) * 64],
          16, 0, 0);
    }
    __syncthreads();  // drains vmcnt: tiles resident
#pragma unroll
    for (int kk = 0; kk < 2; ++kk) {
      bf16x8 a[4], b[4];
#pragma unroll
      for (int m = 0; m < 4; ++m)
        a[m] = __builtin_bit_cast(bf16x8, *reinterpret_cast<const short8v*>(
            &As[(wr * 64 + m * 16 + l15) * 64 + kk * 32 + lg * 8]));
#pragma unroll
      for (int n = 0; n < 4; ++n)
        b[n] = __builtin_bit_cast(bf16x8, *reinterpret_cast<const short8v*>(
            &Bs[(wc * 64 + n * 16 + l15) * 64 + kk * 32 + lg * 8]));
#pragma unroll
      for (int m = 0; m < 4; ++m)
#pragma unroll
        for (int n = 0; n < 4; ++n)
          acc[m][n] = __builtin_amdgcn_mfma_f32_16x16x32_bf16(a[m], b[n], acc[m][n], 0, 0, 0);
    }
  }

  // epilogue: D lane(l) reg j -> row lg*4+j, col l15 (m89)
#pragma unroll
  for (int m = 0; m < 4; ++m) {
#pragma unroll
    for (int j = 0; j < 4; ++j) {
      const size_t row = (size_t)(bm + wr * 64 + m * 16 + lg * 4 + j);
#pragma unroll
      for (int n = 0; n < 4; ++n) {
        const int col = bn + wc * 64 + n * 16 + l15;
        if (BF16_OUT)
          ((unsigned short*)C)[row * N + col] = f2bf(acc[m][n][j]);
        else
          ((float*)C)[row * N + col] = acc[m][n][j];
      }
    }
  }
}

// ---------------------------------------------------------------------------
// W[K][N] f32  ->  Wt[N][K] bf16   (32x32 LDS tiles, conflict-free)
// ---------------------------------------------------------------------------
__global__ __launch_bounds__(256) void transpose_cast(
    const float* __restrict__ W, unsigned short* __restrict__ Wt, int K, int N) {
  __shared__ float tile[32][33];
  const int tx = threadIdx.x & 31, ty = threadIdx.x >> 5;
  const int n0 = blockIdx.x * 32, k0 = blockIdx.y * 32;
#pragma unroll
  for (int i = 0; i < 4; ++i)
    tile[ty + i * 8][tx] = W[(size_t)(k0 + ty + i * 8) * N + n0 + tx];
  __syncthreads();
#pragma unroll
  for (int i = 0; i < 4; ++i)
    Wt[(size_t)(n0 + ty + i * 8) * K + k0 + tx] = f2bf(tile[tx][ty + i * 8]);
}

__global__ __launch_bounds__(256) void cast_f32_bf16(
    const float* __restrict__ in, unsigned short* __restrict__ out) {
  const int i = (blockIdx.x * 256 + threadIdx.x) * 8;
  float4 a = *reinterpret_cast<const float4*>(&in[i]);
  float4 b = *reinterpret_cast<const float4*>(&in[i + 4]);
  short8v s;
  s[0] = f2bf(a.x); s[1] = f2bf(a.y); s[2] = f2bf(a.z); s[3] = f2bf(a.w);
  s[4] = f2bf(b.x); s[5] = f2bf(b.y); s[6] = f2bf(b.z); s[7] = f2bf(b.w);
  *reinterpret_cast<short8v*>(&out[i]) = s;
}

// ---------------------------------------------------------------------------
// RoPE + xPos in place on bf16 buffer (f32 math inside).
// extra_scale folds 1/sqrt(128) into q. invert=1 for k.
// ---------------------------------------------------------------------------
__global__ __launch_bounds__(256) void rope_xpos_ip(
    unsigned short* __restrict__ buf, int nh_shift, int invert, float extra_scale) {
  const int idx = blockIdx.x * 256 + threadIdx.x;
  const int dp  = idx & 63;
  const int tmp = idx >> 6;
  const int h   = tmp & ((1 << nh_shift) - 1);
  const int row = tmp >> nh_shift;
  const int s   = row & (SLEN - 1);

  const float inv_freq = expf(-(float)dp * (9.210340371976184f / 64.0f));
  const float ang = (float)s * inv_freq;
  float sn, cs;
  sincosf(ang, &sn, &cs);

  unsigned short* p = buf + ((size_t)row << (nh_shift + 7)) + ((size_t)h << 7);
  const float x0 = bf2f(p[dp]);
  const float x1 = bf2f(p[dp + 64]);
  float y0 = x0 * cs - x1 * sn;
  float y1 = x1 * cs + x0 * sn;

  const float scl = ((float)s + 256.0f) / 512.0f;
  float se_even = invert ? (1.0f / scl) : scl;
  float se_odd  = invert ? scl : (1.0f / scl);
  float se = ((dp & 1) ? se_odd : se_even) * extra_scale;

  p[dp]      = f2bf(y0 * se);
  p[dp + 64] = f2bf(y1 * se);
}

// ---------------------------------------------------------------------------
// MFMA flash attention (unchanged from R2 except bf16 output).
// ---------------------------------------------------------------------------
__global__ __launch_bounds__(256) void flash_attn_mfma(
    const unsigned short* __restrict__ qb, const unsigned short* __restrict__ kb,
    const unsigned short* __restrict__ vb, unsigned short* __restrict__ o) {
  const int bid = blockIdx.x;
  const int qt  = bid & 31;
  const int bh  = bid >> 5;
  const int h   = bh & (NH - 1);
  const int b   = bh >> 4;
  const int kvh = h >> 2;

  __shared__ __align__(16) unsigned char smem[53248];
  unsigned short* Ks = (unsigned short*)(smem);
  unsigned short* Vt = (unsigned short*)(smem + 17408);
  unsigned short* Qs = (unsigned short*)(smem + 35840);
  unsigned short* Ps = Qs;

  const int t    = threadIdx.x;
  const int lane = t & 63;
  const int w    = t >> 6;
  const int lg   = lane >> 4;
  const int l15  = lane & 15;

  for (int idx = t; idx < 64 * 16; idx += 256) {
    int r = idx >> 4, c8 = idx & 15;
    short8v qv = *reinterpret_cast<const short8v*>(
        &qb[((size_t)(b * SLEN + qt * 64 + r) * NH + h) * HD + c8 * 8]);
    *reinterpret_cast<short8v*>(&Qs[r * 136 + c8 * 8]) = qv;
  }
  __syncthreads();

  bf16x8 qfrag[4];
  {
    const unsigned short* qrow = &Qs[(w * 16 + l15) * 136];
#pragma unroll
    for (int kc = 0; kc < 4; ++kc)
      qfrag[kc] = __builtin_bit_cast(bf16x8,
          *reinterpret_cast<const short8v*>(&qrow[kc * 32 + lg * 8]));
  }

  f32x4 Oacc[8];
#pragma unroll
  for (int dt = 0; dt < 8; ++dt) Oacc[dt] = (f32x4){0.f, 0.f, 0.f, 0.f};
  float m_run[4] = {-1e30f, -1e30f, -1e30f, -1e30f};
  float l_run[4] = {0.f, 0.f, 0.f, 0.f};

  for (int kt = 0; kt <= qt; ++kt) {
    __syncthreads();
    for (int idx = t; idx < 64 * 16; idx += 256) {
      int r = idx >> 4, c8 = idx & 15;
      short8v kv = *reinterpret_cast<const short8v*>(
          &kb[((size_t)(b * SLEN + kt * 64 + r) * NKV + kvh) * HD + c8 * 8]);
      *reinterpret_cast<short8v*>(&Ks[r * 136 + c8 * 8]) = kv;
    }
    for (int idx = t; idx < 64 * 16; idx += 256) {
      int r = idx & 63, c8 = idx >> 6;
      short8v vv = *reinterpret_cast<const short8v*>(
          &vb[((size_t)(b * SLEN + kt * 64 + r) * NKV + kvh) * HD + c8 * 8]);
#pragma unroll
      for (int j = 0; j < 8; ++j) Vt[(c8 * 8 + j) * 72 + r] = (unsigned short)vv[j];
    }
    __syncthreads();

    f32x4 S[4];
#pragma unroll
    for (int ct = 0; ct < 4; ++ct) {
      f32x4 acc = (f32x4){0.f, 0.f, 0.f, 0.f};
      const unsigned short* krow = &Ks[(ct * 16 + l15) * 136];
#pragma unroll
      for (int kc = 0; kc < 4; ++kc) {
        bf16x8 kf = __builtin_bit_cast(bf16x8,
            *reinterpret_cast<const short8v*>(&krow[kc * 32 + lg * 8]));
        acc = __builtin_amdgcn_mfma_f32_16x16x32_bf16(qfrag[kc], kf, acc, 0, 0, 0);
      }
      S[ct] = acc;
    }
    if (kt == qt) {
#pragma unroll
      for (int ct = 0; ct < 4; ++ct) {
        int col = ct * 16 + l15;
#pragma unroll
        for (int j = 0; j < 4; ++j) {
          int row = w * 16 + lg * 4 + j;
          if (col > row) S[ct][j] = -1e30f;
        }
      }
    }
    float f_j[4];
#pragma unroll
    for (int j = 0; j < 4; ++j) {
      float mx = fmaxf(fmaxf(S[0][j], S[1][j]), fmaxf(S[2][j], S[3][j]));
      mx = fmaxf(mx, __shfl_xor(mx, 1));
      mx = fmaxf(mx, __shfl_xor(mx, 2));
      mx = fmaxf(mx, __shfl_xor(mx, 4));
      mx = fmaxf(mx, __shfl_xor(mx, 8));
      float m_new = fmaxf(m_run[j], mx);
      float f = __expf(m_run[j] - m_new);
      m_run[j] = m_new;
      f_j[j] = f;
      float ps = 0.f;
#pragma unroll
      for (int ct = 0; ct < 4; ++ct) {
        float pv = __expf(S[ct][j] - m_new);
        ps += pv;
        Ps[w * 1152 + (lg * 4 + j) * 72 + ct * 16 + l15] = f2bf(pv);
      }
      ps += __shfl_xor(ps, 1);
      ps += __shfl_xor(ps, 2);
      ps += __shfl_xor(ps, 4);
      ps += __shfl_xor(ps, 8);
      l_run[j] = l_run[j] * f + ps;
    }
    __syncthreads();

#pragma unroll
    for (int dt = 0; dt < 8; ++dt) {
#pragma unroll
      for (int j = 0; j < 4; ++j) Oacc[dt][j] *= f_j[j];
    }
    const unsigned short* prow = &Ps[w * 1152 + l15 * 72];
#pragma unroll
    for (int kc = 0; kc < 2; ++kc) {
      bf16x8 pf = __builtin_bit_cast(bf16x8,
          *reinterpret_cast<const short8v*>(&prow[kc * 32 + lg * 8]));
#pragma unroll
      for (int dt = 0; dt < 8; ++dt) {
        bf16x8 vf = __builtin_bit_cast(bf16x8,
            *reinterpret_cast<const short8v*>(&Vt[(dt * 16 + l15) * 72 + kc * 32 + lg * 8]));
        Oacc[dt] = __builtin_amdgcn_mfma_f32_16x16x32_bf16(pf, vf, Oacc[dt], 0, 0, 0);
      }
    }
  }

  float linv[4];
#pragma unroll
  for (int j = 0; j < 4; ++j) linv[j] = 1.0f / l_run[j];
#pragma unroll
  for (int dt = 0; dt < 8; ++dt) {
#pragma unroll
    for (int j = 0; j < 4; ++j) {
      size_t row = (size_t)(b * SLEN + qt * 64 + w * 16 + lg * 4 + j);
      o[row * 2048 + h * HD + dt * 16 + l15] = f2bf(Oacc[dt][j] * linv[j]);
    }
  }
}

// ---------------------------------------------------------------------------
extern "C" void kernel_launch(void* const* d_in, const int* in_sizes, int n_in,
                              void* d_out, int out_size, void* d_ws, size_t ws_size,
                              hipStream_t stream) {
  (void)in_sizes; (void)n_in; (void)out_size; (void)ws_size;
  const float* x  = (const float*)d_in[0];
  const float* Wq = (const float*)d_in[1];
  const float* Wk = (const float*)d_in[2];
  const float* Wv = (const float*)d_in[3];
  const float* Wo = (const float*)d_in[4];
  float* out = (float*)d_out;

  unsigned char* ws = (unsigned char*)d_ws;
  const size_t MB = 1024 * 1024;
  unsigned short* xb   = (unsigned short*)(ws);             // 16 MB  4096x2048
  unsigned short* Wqt  = (unsigned short*)(ws + 16 * MB);   //  8 MB  2048x2048
  unsigned short* Wkt  = (unsigned short*)(ws + 24 * MB);   //  2 MB   512x2048
  unsigned short* Wvt  = (unsigned short*)(ws + 26 * MB);   //  2 MB   512x2048
  unsigned short* Wot  = (unsigned short*)(ws + 28 * MB);   //  8 MB  2048x2048
  unsigned short* qb   = (unsigned short*)(ws + 36 * MB);   // 16 MB
  unsigned short* kb   = (unsigned short*)(ws + 52 * MB);   //  4 MB
  unsigned short* vb   = (unsigned short*)(ws + 56 * MB);   //  4 MB
  unsigned short* attn = (unsigned short*)(ws + 60 * MB);   // 16 MB

  const int M = BDIM * SLEN;  // 4096
  dim3 blk(256);

  cast_f32_bf16<<<(M * 2048) / (256 * 8), blk, 0, stream>>>(x, xb);
  transpose_cast<<<dim3(64, 64), blk, 0, stream>>>(Wq, Wqt, 2048, 2048);
  transpose_cast<<<dim3(16, 64), blk, 0, stream>>>(Wk, Wkt, 2048, 512);
  transpose_cast<<<dim3(16, 64), blk, 0, stream>>>(Wv, Wvt, 2048, 512);
  transpose_cast<<<dim3(64, 64), blk, 0, stream>>>(Wo, Wot, 2048, 2048);

  gemm_mfma_bt<true><<<dim3(2048 / 128, M / 128), blk, 0, stream>>>(
      xb, Wqt, qb, M, 2048, 2048);
  gemm_mfma_bt<true><<<dim3(512 / 128, M / 128), blk, 0, stream>>>(
      xb, Wkt, kb, M, 512, 2048);
  gemm_mfma_bt<true><<<dim3(512 / 128, M / 128), blk, 0, stream>>>(
      xb, Wvt, vb, M, 512, 2048);

  rope_xpos_ip<<<(M * NH * 64) / 256, blk, 0, stream>>>(
      qb, 4, 0, 0.088388347648318447f);
  rope_xpos_ip<<<(M * NKV * 64) / 256, blk, 0, stream>>>(kb, 2, 1, 1.0f);

  flash_attn_mfma<<<BDIM * NH * (SLEN / 64), blk, 0, stream>>>(qb, kb, vb, attn);

  gemm_mfma_bt<false><<<dim3(2048 / 128, M / 128), blk, 0, stream>>>(
      attn, Wot, out, M, 2048, 2048);
}

// Round 4
// 364.504 us; speedup vs baseline: 25.1654x; 1.3004x over previous
//
#include <hip/hip_runtime.h>
#include <math.h>

#define BDIM 2
#define SLEN 2048
#define NH 16
#define NKV 4
#define HD 128

typedef __attribute__((ext_vector_type(8))) short short8v;
typedef __attribute__((ext_vector_type(8))) __bf16 bf16x8;
typedef __attribute__((ext_vector_type(4))) float f32x4;

__device__ inline unsigned short f2bf(float x) {
  unsigned int u = __builtin_bit_cast(unsigned int, x);
  unsigned int r = (u + 0x7fffu + ((u >> 16) & 1u)) >> 16;
  return (unsigned short)r;
}
__device__ inline float bf2f(unsigned short b) {
  unsigned int u = ((unsigned int)b) << 16;
  return __builtin_bit_cast(float, u);
}

// ---------------------------------------------------------------------------
// bf16 MFMA GEMM, m97 structure (unchanged from R3).
// ---------------------------------------------------------------------------
template <bool BF16_OUT>
__global__ __launch_bounds__(256) void gemm_mfma_bt(
    const unsigned short* __restrict__ A, const unsigned short* __restrict__ Bt,
    void* __restrict__ C, int M, int N, int K) {
  __shared__ __align__(16) unsigned short As[128 * 64];
  __shared__ __align__(16) unsigned short Bs[128 * 64];
  const int t    = threadIdx.x;
  const int lane = t & 63;
  const int w    = t >> 6;
  const int lg   = lane >> 4, l15 = lane & 15;
  const int wr   = w >> 1,    wc  = w & 1;
  const int bm = blockIdx.y * 128, bn = blockIdx.x * 128;

  const int srow = w * 32 + (lane >> 3);
  const int scol = (lane & 7) * 8;
  const unsigned short* gA = &A[(size_t)(bm + srow) * K + scol];
  const unsigned short* gB = &Bt[(size_t)(bn + srow) * K + scol];

  f32x4 acc[4][4];
#pragma unroll
  for (int m = 0; m < 4; ++m)
#pragma unroll
    for (int n = 0; n < 4; ++n) acc[m][n] = (f32x4){0.f, 0.f, 0.f, 0.f};

  for (int k0 = 0; k0 < K; k0 += 64) {
    __syncthreads();
#pragma unroll
    for (int i = 0; i < 4; ++i) {
      __builtin_amdgcn_global_load_lds(
          (const __attribute__((address_space(1))) unsigned int*)(gA + (size_t)i * 8 * K + k0),
          (__attribute__((address_space(3))) unsigned int*)&As[(w * 32 + i * 8) * 64],
          16, 0, 0);
      __builtin_amdgcn_global_load_lds(
          (const __attribute__((address_space(1))) unsigned int*)(gB + (size_t)i * 8 * K + k0),
          (__attribute__((address_space(3))) unsigned int*)&Bs[(w * 32 + i * 8) * 64],
          16, 0, 0);
    }
    __syncthreads();
#pragma unroll
    for (int kk = 0; kk < 2; ++kk) {
      bf16x8 a[4], b[4];
#pragma unroll
      for (int m = 0; m < 4; ++m)
        a[m] = __builtin_bit_cast(bf16x8, *reinterpret_cast<const short8v*>(
            &As[(wr * 64 + m * 16 + l15) * 64 + kk * 32 + lg * 8]));
#pragma unroll
      for (int n = 0; n < 4; ++n)
        b[n] = __builtin_bit_cast(bf16x8, *reinterpret_cast<const short8v*>(
            &Bs[(wc * 64 + n * 16 + l15) * 64 + kk * 32 + lg * 8]));
#pragma unroll
      for (int m = 0; m < 4; ++m)
#pragma unroll
        for (int n = 0; n < 4; ++n)
          acc[m][n] = __builtin_amdgcn_mfma_f32_16x16x32_bf16(a[m], b[n], acc[m][n], 0, 0, 0);
    }
  }
#pragma unroll
  for (int m = 0; m < 4; ++m) {
#pragma unroll
    for (int j = 0; j < 4; ++j) {
      const size_t row = (size_t)(bm + wr * 64 + m * 16 + lg * 4 + j);
#pragma unroll
      for (int n = 0; n < 4; ++n) {
        const int col = bn + wc * 64 + n * 16 + l15;
        if (BF16_OUT)
          ((unsigned short*)C)[row * N + col] = f2bf(acc[m][n][j]);
        else
          ((float*)C)[row * N + col] = acc[m][n][j];
      }
    }
  }
}

// ---------------------------------------------------------------------------
__global__ __launch_bounds__(256) void transpose_cast(
    const float* __restrict__ W, unsigned short* __restrict__ Wt, int K, int N) {
  __shared__ float tile[32][33];
  const int tx = threadIdx.x & 31, ty = threadIdx.x >> 5;
  const int n0 = blockIdx.x * 32, k0 = blockIdx.y * 32;
#pragma unroll
  for (int i = 0; i < 4; ++i)
    tile[ty + i * 8][tx] = W[(size_t)(k0 + ty + i * 8) * N + n0 + tx];
  __syncthreads();
#pragma unroll
  for (int i = 0; i < 4; ++i)
    Wt[(size_t)(n0 + ty + i * 8) * K + k0 + tx] = f2bf(tile[tx][ty + i * 8]);
}

__global__ __launch_bounds__(256) void cast_f32_bf16(
    const float* __restrict__ in, unsigned short* __restrict__ out) {
  const int i = (blockIdx.x * 256 + threadIdx.x) * 8;
  float4 a = *reinterpret_cast<const float4*>(&in[i]);
  float4 b = *reinterpret_cast<const float4*>(&in[i + 4]);
  short8v s;
  s[0] = f2bf(a.x); s[1] = f2bf(a.y); s[2] = f2bf(a.z); s[3] = f2bf(a.w);
  s[4] = f2bf(b.x); s[5] = f2bf(b.y); s[6] = f2bf(b.z); s[7] = f2bf(b.w);
  *reinterpret_cast<short8v*>(&out[i]) = s;
}

// ---------------------------------------------------------------------------
// RoPE + xPos in place on bf16, generic row stride (q: 2048, k in kvb: 1024).
// ---------------------------------------------------------------------------
__global__ __launch_bounds__(256) void rope_xpos_ip(
    unsigned short* __restrict__ buf, int row_stride, int nh_shift, int invert,
    float extra_scale) {
  const int idx = blockIdx.x * 256 + threadIdx.x;
  const int dp  = idx & 63;
  const int tmp = idx >> 6;
  const int h   = tmp & ((1 << nh_shift) - 1);
  const int row = tmp >> nh_shift;
  const int s   = row & (SLEN - 1);

  const float inv_freq = expf(-(float)dp * (9.210340371976184f / 64.0f));
  const float ang = (float)s * inv_freq;
  float sn, cs;
  sincosf(ang, &sn, &cs);

  unsigned short* p = buf + (size_t)row * row_stride + h * HD;
  const float x0 = bf2f(p[dp]);
  const float x1 = bf2f(p[dp + 64]);
  float y0 = x0 * cs - x1 * sn;
  float y1 = x1 * cs + x0 * sn;

  const float scl = ((float)s + 256.0f) / 512.0f;
  float se_even = invert ? (1.0f / scl) : scl;
  float se_odd  = invert ? scl : (1.0f / scl);
  float se = ((dp & 1) ? se_odd : se_even) * extra_scale;

  p[dp]      = f2bf(y0 * se);
  p[dp + 64] = f2bf(y1 * se);
}

// ---------------------------------------------------------------------------
// Flash attention v2: XOR-swizzled LDS, reg-prefetch (T14), 2 barriers/tile,
// setprio (T5), balanced causal qt pairing, no Q LDS stage.
// kvb layout: [row][1024] = K at kvh*128, V at 512 + kvh*128.
// LDS: Ks [64][128] swz, Vt [128][64] swz (d-major), Ps per-wave [16][88].
// ---------------------------------------------------------------------------
__global__ __launch_bounds__(256) void flash_attn_v2(
    const unsigned short* __restrict__ qb, const unsigned short* __restrict__ kvb,
    unsigned short* __restrict__ o) {
  const int bid = blockIdx.x;
  const int u   = bid & 31;
  const int qt  = (u & 1) ? (31 - (u >> 1)) : (u >> 1);  // balanced pairing
  const int bh  = bid >> 5;
  const int h   = bh & (NH - 1);
  const int b   = bh >> 4;
  const int kvh = h >> 2;

  __shared__ __align__(16) unsigned char smem[44032];
  unsigned short* Ks = (unsigned short*)smem;            // 64*128 swz
  unsigned short* Vt = (unsigned short*)(smem + 16384);  // 128*64 swz, d-major
  unsigned short* Ps = (unsigned short*)(smem + 32768);  // 4 * [16][88]

  const int t    = threadIdx.x;
  const int lane = t & 63;
  const int w    = t >> 6;
  const int lg   = lane >> 4;
  const int l15  = lane & 15;

  // ---- Q fragments directly from global
  bf16x8 qfrag[4];
  {
    const size_t qrow =
        ((size_t)(b * SLEN + qt * 64 + w * 16 + l15)) * (NH * HD) + h * HD;
#pragma unroll
    for (int kc = 0; kc < 4; ++kc)
      qfrag[kc] = __builtin_bit_cast(bf16x8,
          *reinterpret_cast<const short8v*>(&qb[qrow + kc * 32 + lg * 8]));
  }

  short8v kreg[4], vreg0[2], vreg1[2];
  const int kr_base = t >> 4, kc8 = t & 15;
  const int vr2 = t & 31, vc8_base = t >> 5;  // vc8 = vc8_base + 8*i

#define LOAD_TILE(kt)                                                          \
  {                                                                            \
    const size_t kbase = ((size_t)(b * SLEN + (kt) * 64)) * 1024 + kvh * 128;  \
    _Pragma("unroll") for (int i = 0; i < 4; ++i)                              \
        kreg[i] = *reinterpret_cast<const short8v*>(                           \
            &kvb[kbase + (size_t)(kr_base + i * 16) * 1024 + kc8 * 8]);        \
    const size_t vbase = kbase + 512;                                          \
    _Pragma("unroll") for (int i = 0; i < 2; ++i) {                            \
      const int c8 = vc8_base + i * 8;                                         \
      vreg0[i] = *reinterpret_cast<const short8v*>(                            \
          &kvb[vbase + (size_t)(2 * vr2) * 1024 + c8 * 8]);                    \
      vreg1[i] = *reinterpret_cast<const short8v*>(                            \
          &kvb[vbase + (size_t)(2 * vr2 + 1) * 1024 + c8 * 8]);                \
    }                                                                          \
  }

#define STORE_TILE()                                                           \
  {                                                                            \
    _Pragma("unroll") for (int i = 0; i < 4; ++i) {                            \
      const int r = kr_base + i * 16;                                          \
      *reinterpret_cast<short8v*>(&Ks[r * 128 + ((kc8 * 8) ^ ((r & 7) << 3))]) \
          = kreg[i];                                                           \
    }                                                                          \
    _Pragma("unroll") for (int i = 0; i < 2; ++i) {                            \
      const int c8 = vc8_base + i * 8;                                         \
      _Pragma("unroll") for (int j = 0; j < 8; ++j) {                          \
        const int d = c8 * 8 + j;                                              \
        unsigned int wv = (unsigned int)(unsigned short)vreg0[i][j] |          \
                          ((unsigned int)(unsigned short)vreg1[i][j] << 16);   \
        ((unsigned int*)Vt)[d * 32 + (vr2 ^ ((d & 7) << 2))] = wv;             \
      }                                                                        \
    }                                                                          \
  }

  f32x4 Oacc[8];
#pragma unroll
  for (int dt = 0; dt < 8; ++dt) Oacc[dt] = (f32x4){0.f, 0.f, 0.f, 0.f};
  float m_run[4] = {-1e30f, -1e30f, -1e30f, -1e30f};
  float l_run[4] = {0.f, 0.f, 0.f, 0.f};

  LOAD_TILE(0)
  STORE_TILE()
  __syncthreads();

  for (int kt = 0; kt <= qt; ++kt) {
    if (kt < qt) LOAD_TILE(kt + 1)   // prefetch into regs; lands by next barrier

    // ---- QK^T
    f32x4 S[4];
    __builtin_amdgcn_s_setprio(1);
#pragma unroll
    for (int ct = 0; ct < 4; ++ct) {
      f32x4 acc = (f32x4){0.f, 0.f, 0.f, 0.f};
      const int row = ct * 16 + l15;
#pragma unroll
      for (int kc = 0; kc < 4; ++kc) {
        bf16x8 kf = __builtin_bit_cast(bf16x8, *reinterpret_cast<const short8v*>(
            &Ks[row * 128 + ((kc * 32 + lg * 8) ^ ((row & 7) << 3))]));
        acc = __builtin_amdgcn_mfma_f32_16x16x32_bf16(qfrag[kc], kf, acc, 0, 0, 0);
      }
      S[ct] = acc;
    }
    __builtin_amdgcn_s_setprio(0);

    if (kt == qt) {
#pragma unroll
      for (int ct = 0; ct < 4; ++ct) {
        const int col = ct * 16 + l15;
#pragma unroll
        for (int j = 0; j < 4; ++j) {
          const int row = w * 16 + lg * 4 + j;
          if (col > row) S[ct][j] = -1e30f;
        }
      }
    }

    // ---- online softmax (per row j; stats across the 16-lane col group)
    float f_j[4];
#pragma unroll
    for (int j = 0; j < 4; ++j) {
      float mx = fmaxf(fmaxf(S[0][j], S[1][j]), fmaxf(S[2][j], S[3][j]));
      mx = fmaxf(mx, __shfl_xor(mx, 1));
      mx = fmaxf(mx, __shfl_xor(mx, 2));
      mx = fmaxf(mx, __shfl_xor(mx, 4));
      mx = fmaxf(mx, __shfl_xor(mx, 8));
      const float m_new = fmaxf(m_run[j], mx);
      const float f = __expf(m_run[j] - m_new);
      m_run[j] = m_new;
      f_j[j] = f;
      float ps = 0.f;
#pragma unroll
      for (int ct = 0; ct < 4; ++ct) {
        const float pv = __expf(S[ct][j] - m_new);
        ps += pv;
        Ps[w * 1408 + (lg * 4 + j) * 88 + ct * 16 + l15] = f2bf(pv);
      }
      ps += __shfl_xor(ps, 1);
      ps += __shfl_xor(ps, 2);
      ps += __shfl_xor(ps, 4);
      ps += __shfl_xor(ps, 8);
      l_run[j] = l_run[j] * f + ps;
    }

    // ---- rescale O then PV (Ps is wave-private: lgkmcnt only, no barrier)
#pragma unroll
    for (int dt = 0; dt < 8; ++dt) {
#pragma unroll
      for (int j = 0; j < 4; ++j) Oacc[dt][j] *= f_j[j];
    }
    const unsigned short* prow = &Ps[w * 1408 + l15 * 88];
#pragma unroll
    for (int kc = 0; kc < 2; ++kc) {
      bf16x8 pf = __builtin_bit_cast(bf16x8,
          *reinterpret_cast<const short8v*>(&prow[kc * 32 + lg * 8]));
      __builtin_amdgcn_s_setprio(1);
#pragma unroll
      for (int dt = 0; dt < 8; ++dt) {
        const int d = dt * 16 + l15;
        bf16x8 vf = __builtin_bit_cast(bf16x8, *reinterpret_cast<const short8v*>(
            &Vt[d * 64 + ((kc * 32 + lg * 8) ^ ((d & 7) << 3))]));
        Oacc[dt] = __builtin_amdgcn_mfma_f32_16x16x32_bf16(pf, vf, Oacc[dt], 0, 0, 0);
      }
      __builtin_amdgcn_s_setprio(0);
    }

    __syncthreads();                 // all waves done reading Ks/Vt
    if (kt < qt) {
      STORE_TILE()                   // prefetched regs -> LDS
      __syncthreads();               // writes visible
    }
  }

  float linv[4];
#pragma unroll
  for (int j = 0; j < 4; ++j) linv[j] = 1.0f / l_run[j];
#pragma unroll
  for (int dt = 0; dt < 8; ++dt) {
#pragma unroll
    for (int j = 0; j < 4; ++j) {
      const size_t row = (size_t)(b * SLEN + qt * 64 + w * 16 + lg * 4 + j);
      o[row * 2048 + h * HD + dt * 16 + l15] = f2bf(Oacc[dt][j] * linv[j]);
    }
  }
#undef LOAD_TILE
#undef STORE_TILE
}

// ---------------------------------------------------------------------------
extern "C" void kernel_launch(void* const* d_in, const int* in_sizes, int n_in,
                              void* d_out, int out_size, void* d_ws, size_t ws_size,
                              hipStream_t stream) {
  (void)in_sizes; (void)n_in; (void)out_size; (void)ws_size;
  const float* x  = (const float*)d_in[0];
  const float* Wq = (const float*)d_in[1];
  const float* Wk = (const float*)d_in[2];
  const float* Wv = (const float*)d_in[3];
  const float* Wo = (const float*)d_in[4];
  float* out = (float*)d_out;

  unsigned char* ws = (unsigned char*)d_ws;
  const size_t MB = 1024 * 1024;
  unsigned short* xb   = (unsigned short*)(ws);            // 16 MB 4096x2048
  unsigned short* Wqt  = (unsigned short*)(ws + 16 * MB);  //  8 MB 2048x2048
  unsigned short* Wkvt = (unsigned short*)(ws + 24 * MB);  //  4 MB 1024x2048
  unsigned short* Wot  = (unsigned short*)(ws + 28 * MB);  //  8 MB 2048x2048
  unsigned short* qb   = (unsigned short*)(ws + 36 * MB);  // 16 MB 4096x2048
  unsigned short* kvb  = (unsigned short*)(ws + 52 * MB);  //  8 MB 4096x1024
  unsigned short* attn = (unsigned short*)(ws + 60 * MB);  // 16 MB

  const int M = BDIM * SLEN;  // 4096
  dim3 blk(256);

  cast_f32_bf16<<<(M * 2048) / (256 * 8), blk, 0, stream>>>(x, xb);
  transpose_cast<<<dim3(64, 64), blk, 0, stream>>>(Wq, Wqt, 2048, 2048);
  transpose_cast<<<dim3(16, 64), blk, 0, stream>>>(Wk, Wkvt, 2048, 512);
  transpose_cast<<<dim3(16, 64), blk, 0, stream>>>(
      Wv, Wkvt + (size_t)512 * 2048, 2048, 512);
  transpose_cast<<<dim3(64, 64), blk, 0, stream>>>(Wo, Wot, 2048, 2048);

  gemm_mfma_bt<true><<<dim3(16, 32), blk, 0, stream>>>(xb, Wqt, qb, M, 2048, 2048);
  gemm_mfma_bt<true><<<dim3(8, 32), blk, 0, stream>>>(xb, Wkvt, kvb, M, 1024, 2048);

  rope_xpos_ip<<<(M * NH * 64) / 256, blk, 0, stream>>>(
      qb, 2048, 4, 0, 0.088388347648318447f);
  rope_xpos_ip<<<(M * NKV * 64) / 256, blk, 0, stream>>>(kvb, 1024, 2, 1, 1.0f);

  flash_attn_v2<<<BDIM * NH * (SLEN / 64), blk, 0, stream>>>(qb, kvb, attn);

  gemm_mfma_bt<false><<<dim3(16, 32), blk, 0, stream>>>(attn, Wot, out, M, 2048, 2048);
}

// Round 5
// 298.651 us; speedup vs baseline: 30.7144x; 1.2205x over previous
//
#include <hip/hip_runtime.h>
#include <math.h>

#define BDIM 2
#define SLEN 2048
#define NH 16
#define NKV 4
#define HD 128

typedef __attribute__((ext_vector_type(8))) short short8v;
typedef __attribute__((ext_vector_type(4))) short short4v;
typedef __attribute__((ext_vector_type(8))) __bf16 bf16x8;
typedef __attribute__((ext_vector_type(4))) float f32x4;

__device__ inline unsigned short f2bf(float x) {
  unsigned int u = __builtin_bit_cast(unsigned int, x);
  unsigned int r = (u + 0x7fffu + ((u >> 16) & 1u)) >> 16;
  return (unsigned short)r;
}
__device__ inline float bf2f(unsigned short b) {
  unsigned int u = ((unsigned int)b) << 16;
  return __builtin_bit_cast(float, u);
}

// ---------------------------------------------------------------------------
// bf16 MFMA GEMM, m97 structure (unchanged).
// ---------------------------------------------------------------------------
template <bool BF16_OUT>
__global__ __launch_bounds__(256) void gemm_mfma_bt(
    const unsigned short* __restrict__ A, const unsigned short* __restrict__ Bt,
    void* __restrict__ C, int M, int N, int K) {
  __shared__ __align__(16) unsigned short As[128 * 64];
  __shared__ __align__(16) unsigned short Bs[128 * 64];
  const int t    = threadIdx.x;
  const int lane = t & 63;
  const int w    = t >> 6;
  const int lg   = lane >> 4, l15 = lane & 15;
  const int wr   = w >> 1,    wc  = w & 1;
  const int bm = blockIdx.y * 128, bn = blockIdx.x * 128;

  const int srow = w * 32 + (lane >> 3);
  const int scol = (lane & 7) * 8;
  const unsigned short* gA = &A[(size_t)(bm + srow) * K + scol];
  const unsigned short* gB = &Bt[(size_t)(bn + srow) * K + scol];

  f32x4 acc[4][4];
#pragma unroll
  for (int m = 0; m < 4; ++m)
#pragma unroll
    for (int n = 0; n < 4; ++n) acc[m][n] = (f32x4){0.f, 0.f, 0.f, 0.f};

  for (int k0 = 0; k0 < K; k0 += 64) {
    __syncthreads();
#pragma unroll
    for (int i = 0; i < 4; ++i) {
      __builtin_amdgcn_global_load_lds(
          (const __attribute__((address_space(1))) unsigned int*)(gA + (size_t)i * 8 * K + k0),
          (__attribute__((address_space(3))) unsigned int*)&As[(w * 32 + i * 8) * 64],
          16, 0, 0);
      __builtin_amdgcn_global_load_lds(
          (const __attribute__((address_space(1))) unsigned int*)(gB + (size_t)i * 8 * K + k0),
          (__attribute__((address_space(3))) unsigned int*)&Bs[(w * 32 + i * 8) * 64],
          16, 0, 0);
    }
    __syncthreads();
#pragma unroll
    for (int kk = 0; kk < 2; ++kk) {
      bf16x8 a[4], b[4];
#pragma unroll
      for (int m = 0; m < 4; ++m)
        a[m] = __builtin_bit_cast(bf16x8, *reinterpret_cast<const short8v*>(
            &As[(wr * 64 + m * 16 + l15) * 64 + kk * 32 + lg * 8]));
#pragma unroll
      for (int n = 0; n < 4; ++n)
        b[n] = __builtin_bit_cast(bf16x8, *reinterpret_cast<const short8v*>(
            &Bs[(wc * 64 + n * 16 + l15) * 64 + kk * 32 + lg * 8]));
#pragma unroll
      for (int m = 0; m < 4; ++m)
#pragma unroll
        for (int n = 0; n < 4; ++n)
          acc[m][n] = __builtin_amdgcn_mfma_f32_16x16x32_bf16(a[m], b[n], acc[m][n], 0, 0, 0);
    }
  }
#pragma unroll
  for (int m = 0; m < 4; ++m) {
#pragma unroll
    for (int j = 0; j < 4; ++j) {
      const size_t row = (size_t)(bm + wr * 64 + m * 16 + lg * 4 + j);
#pragma unroll
      for (int n = 0; n < 4; ++n) {
        const int col = bn + wc * 64 + n * 16 + l15;
        if (BF16_OUT)
          ((unsigned short*)C)[row * N + col] = f2bf(acc[m][n][j]);
        else
          ((float*)C)[row * N + col] = acc[m][n][j];
      }
    }
  }
}

// ---------------------------------------------------------------------------
__global__ __launch_bounds__(256) void transpose_cast(
    const float* __restrict__ W, unsigned short* __restrict__ Wt, int K, int N) {
  __shared__ float tile[32][33];
  const int tx = threadIdx.x & 31, ty = threadIdx.x >> 5;
  const int n0 = blockIdx.x * 32, k0 = blockIdx.y * 32;
#pragma unroll
  for (int i = 0; i < 4; ++i)
    tile[ty + i * 8][tx] = W[(size_t)(k0 + ty + i * 8) * N + n0 + tx];
  __syncthreads();
#pragma unroll
  for (int i = 0; i < 4; ++i)
    Wt[(size_t)(n0 + ty + i * 8) * K + k0 + tx] = f2bf(tile[tx][ty + i * 8]);
}

__global__ __launch_bounds__(256) void cast_f32_bf16(
    const float* __restrict__ in, unsigned short* __restrict__ out) {
  const int i = (blockIdx.x * 256 + threadIdx.x) * 8;
  float4 a = *reinterpret_cast<const float4*>(&in[i]);
  float4 b = *reinterpret_cast<const float4*>(&in[i + 4]);
  short8v s;
  s[0] = f2bf(a.x); s[1] = f2bf(a.y); s[2] = f2bf(a.z); s[3] = f2bf(a.w);
  s[4] = f2bf(b.x); s[5] = f2bf(b.y); s[6] = f2bf(b.z); s[7] = f2bf(b.w);
  *reinterpret_cast<short8v*>(&out[i]) = s;
}

// ---------------------------------------------------------------------------
__global__ __launch_bounds__(256) void rope_xpos_ip(
    unsigned short* __restrict__ buf, int row_stride, int nh_shift, int invert,
    float extra_scale) {
  const int idx = blockIdx.x * 256 + threadIdx.x;
  const int dp  = idx & 63;
  const int tmp = idx >> 6;
  const int h   = tmp & ((1 << nh_shift) - 1);
  const int row = tmp >> nh_shift;
  const int s   = row & (SLEN - 1);

  const float inv_freq = expf(-(float)dp * (9.210340371976184f / 64.0f));
  const float ang = (float)s * inv_freq;
  float sn, cs;
  sincosf(ang, &sn, &cs);

  unsigned short* p = buf + (size_t)row * row_stride + h * HD;
  const float x0 = bf2f(p[dp]);
  const float x1 = bf2f(p[dp + 64]);
  float y0 = x0 * cs - x1 * sn;
  float y1 = x1 * cs + x0 * sn;

  const float scl = ((float)s + 256.0f) / 512.0f;
  float se_even = invert ? (1.0f / scl) : scl;
  float se_odd  = invert ? scl : (1.0f / scl);
  float se = ((dp & 1) ? se_odd : se_even) * extra_scale;

  p[dp]      = f2bf(y0 * se);
  p[dp + 64] = f2bf(y1 * se);
}

// ---------------------------------------------------------------------------
// Flash attention v3: swapped-operand QK^T & PV (lane-local softmax, q=l15),
// double-buffered K/V LDS (1 barrier/tile), reg-prefetch, defer-max (THR=8),
// setprio around MFMA clusters, balanced causal qt pairing.
// kvb layout: [row][1024] = K at kvh*128, V at 512 + kvh*128.
// ---------------------------------------------------------------------------
__global__ __launch_bounds__(256) void flash_attn_v3(
    const unsigned short* __restrict__ qb, const unsigned short* __restrict__ kvb,
    unsigned short* __restrict__ o) {
  const int bid = blockIdx.x;
  const int u   = bid & 31;
  const int qt  = (u & 1) ? (31 - (u >> 1)) : (u >> 1);
  const int bh  = bid >> 5;
  const int h   = bh & (NH - 1);
  const int b   = bh >> 4;
  const int kvh = h >> 2;

  __shared__ __align__(16) unsigned char smem[76800];
  unsigned short* KsBase = (unsigned short*)smem;          // 2 x 64*128 swz
  unsigned int*   VwBase = (unsigned int*)(smem + 32768);  // 2 x 128*32 words swz
  unsigned short* Ps     = (unsigned short*)(smem + 65536); // 4 x [16][88]

  const int t    = threadIdx.x;
  const int lane = t & 63;
  const int w    = t >> 6;
  const int lg   = lane >> 4;
  const int l15  = lane & 15;

  // ---- Q fragments directly from global (Q[q=l15-row of wave band][d-slice])
  bf16x8 qfrag[4];
  {
    const size_t qrow =
        ((size_t)(b * SLEN + qt * 64 + w * 16 + l15)) * (NH * HD) + h * HD;
#pragma unroll
    for (int kc = 0; kc < 4; ++kc)
      qfrag[kc] = __builtin_bit_cast(bf16x8,
          *reinterpret_cast<const short8v*>(&qb[qrow + kc * 32 + lg * 8]));
  }

  short8v kreg[4], vreg0[2], vreg1[2];
  const int kr_base = t >> 4, kc8 = t & 15;
  const int vr2 = t & 31, vc8_base = t >> 5;

#define LOAD_TILE(kt)                                                          \
  {                                                                            \
    const size_t kbase = ((size_t)(b * SLEN + (kt) * 64)) * 1024 + kvh * 128;  \
    _Pragma("unroll") for (int i = 0; i < 4; ++i)                              \
        kreg[i] = *reinterpret_cast<const short8v*>(                           \
            &kvb[kbase + (size_t)(kr_base + i * 16) * 1024 + kc8 * 8]);        \
    const size_t vbase = kbase + 512;                                          \
    _Pragma("unroll") for (int i = 0; i < 2; ++i) {                            \
      const int c8 = vc8_base + i * 8;                                         \
      vreg0[i] = *reinterpret_cast<const short8v*>(                            \
          &kvb[vbase + (size_t)(2 * vr2) * 1024 + c8 * 8]);                    \
      vreg1[i] = *reinterpret_cast<const short8v*>(                            \
          &kvb[vbase + (size_t)(2 * vr2 + 1) * 1024 + c8 * 8]);                \
    }                                                                          \
  }

#define STORE_TILE(bb)                                                         \
  {                                                                            \
    unsigned short* Kb = KsBase + (bb) * 8192;                                 \
    unsigned int*   Vw = VwBase + (bb) * 4096;                                 \
    _Pragma("unroll") for (int i = 0; i < 4; ++i) {                            \
      const int r = kr_base + i * 16;                                          \
      *reinterpret_cast<short8v*>(&Kb[r * 128 + ((kc8 * 8) ^ ((r & 7) << 3))]) \
          = kreg[i];                                                           \
    }                                                                          \
    _Pragma("unroll") for (int i = 0; i < 2; ++i) {                            \
      const int c8 = vc8_base + i * 8;                                         \
      _Pragma("unroll") for (int j = 0; j < 8; ++j) {                          \
        const int d = c8 * 8 + j;                                              \
        unsigned int wv = (unsigned int)(unsigned short)vreg0[i][j] |          \
                          ((unsigned int)(unsigned short)vreg1[i][j] << 16);   \
        Vw[d * 32 + (vr2 ^ ((d & 7) << 2))] = wv;                              \
      }                                                                        \
    }                                                                          \
  }

  f32x4 Oacc[8];  // O[q=l15][d = dt*16 + lg*4 + j]  (O^T D-layout)
#pragma unroll
  for (int dt = 0; dt < 8; ++dt) Oacc[dt] = (f32x4){0.f, 0.f, 0.f, 0.f};
  float m_run = -1e30f, l_run = 0.f;

  LOAD_TILE(0)
  STORE_TILE(0)
  __syncthreads();
  int cur = 0;

  for (int kt = 0; kt <= qt; ++kt) {
    if (kt < qt) LOAD_TILE(kt + 1)

    const unsigned short* Kb = KsBase + cur * 8192;
    const unsigned int*   Vw = VwBase + cur * 4096;

    // ---- S^T = K @ Q^T : lane holds k = ct*16+lg*4+j for its q = l15
    f32x4 S[4];
    __builtin_amdgcn_s_setprio(1);
#pragma unroll
    for (int ct = 0; ct < 4; ++ct) {
      f32x4 acc = (f32x4){0.f, 0.f, 0.f, 0.f};
      const int row = ct * 16 + l15;
#pragma unroll
      for (int kc = 0; kc < 4; ++kc) {
        bf16x8 kf = __builtin_bit_cast(bf16x8, *reinterpret_cast<const short8v*>(
            &Kb[row * 128 + ((kc * 32 + lg * 8) ^ ((row & 7) << 3))]));
        acc = __builtin_amdgcn_mfma_f32_16x16x32_bf16(kf, qfrag[kc], acc, 0, 0, 0);
      }
      S[ct] = acc;
    }
    __builtin_amdgcn_s_setprio(0);

    if (kt == qt) {  // causal: mask k_local > q_local
      const int ql = w * 16 + l15;
#pragma unroll
      for (int ct = 0; ct < 4; ++ct) {
#pragma unroll
        for (int j = 0; j < 4; ++j) {
          if (ct * 16 + lg * 4 + j > ql) S[ct][j] = -1e30f;
        }
      }
    }

    // ---- lane-local softmax (q = l15)
    float pmax = S[0][0];
#pragma unroll
    for (int ct = 0; ct < 4; ++ct)
#pragma unroll
      for (int j = 0; j < 4; ++j) pmax = fmaxf(pmax, S[ct][j]);
    pmax = fmaxf(pmax, __shfl_xor(pmax, 16));
    pmax = fmaxf(pmax, __shfl_xor(pmax, 32));

    const bool defer = __all(pmax - m_run <= 8.0f);
    float m_new, f;
    if (defer) {
      m_new = m_run; f = 1.0f;
    } else {
      m_new = fmaxf(m_run, pmax);
      f = __expf(m_run - m_new);
      m_run = m_new;
    }

    float psum = 0.f;
#pragma unroll
    for (int ct = 0; ct < 4; ++ct) {
      short4v pk;
#pragma unroll
      for (int j = 0; j < 4; ++j) {
        const float pv = __expf(S[ct][j] - m_new);
        psum += pv;
        pk[j] = (short)f2bf(pv);
      }
      *reinterpret_cast<short4v*>(&Ps[w * 1408 + l15 * 88 + ct * 16 + lg * 4]) = pk;
    }
    psum += __shfl_xor(psum, 16);
    psum += __shfl_xor(psum, 32);
    l_run = l_run * f + psum;

    if (!defer) {
#pragma unroll
      for (int dt = 0; dt < 8; ++dt)
#pragma unroll
        for (int j = 0; j < 4; ++j) Oacc[dt][j] *= f;
    }

    // ---- O^T += V^T @ P^T  (A = V^T from Vw, B = P^T from Ps)
    const unsigned short* prow = &Ps[w * 1408 + l15 * 88];
#pragma unroll
    for (int kc = 0; kc < 2; ++kc) {
      bf16x8 pf = __builtin_bit_cast(bf16x8,
          *reinterpret_cast<const short8v*>(&prow[kc * 32 + lg * 8]));
      __builtin_amdgcn_s_setprio(1);
#pragma unroll
      for (int dt = 0; dt < 8; ++dt) {
        const int d = dt * 16 + l15;
        bf16x8 vf = __builtin_bit_cast(bf16x8, *reinterpret_cast<const bf16x8*>(
            &Vw[d * 32 + ((kc * 16 + lg * 4) ^ ((d & 7) << 2))]));
        Oacc[dt] = __builtin_amdgcn_mfma_f32_16x16x32_bf16(vf, pf, Oacc[dt], 0, 0, 0);
      }
      __builtin_amdgcn_s_setprio(0);
    }

    if (kt < qt) STORE_TILE(cur ^ 1)
    __syncthreads();
    cur ^= 1;
  }

  // ---- epilogue: q = l15 for both Oacc and l_run; packed 8B stores
  const float linv = 1.0f / l_run;
  const size_t row = (size_t)(b * SLEN + qt * 64 + w * 16 + l15);
#pragma unroll
  for (int dt = 0; dt < 8; ++dt) {
    short4v ov;
#pragma unroll
    for (int j = 0; j < 4; ++j) ov[j] = (short)f2bf(Oacc[dt][j] * linv);
    *reinterpret_cast<short4v*>(&o[row * 2048 + h * HD + dt * 16 + lg * 4]) = ov;
  }
#undef LOAD_TILE
#undef STORE_TILE
}

// ---------------------------------------------------------------------------
extern "C" void kernel_launch(void* const* d_in, const int* in_sizes, int n_in,
                              void* d_out, int out_size, void* d_ws, size_t ws_size,
                              hipStream_t stream) {
  (void)in_sizes; (void)n_in; (void)out_size; (void)ws_size;
  const float* x  = (const float*)d_in[0];
  const float* Wq = (const float*)d_in[1];
  const float* Wk = (const float*)d_in[2];
  const float* Wv = (const float*)d_in[3];
  const float* Wo = (const float*)d_in[4];
  float* out = (float*)d_out;

  unsigned char* ws = (unsigned char*)d_ws;
  const size_t MB = 1024 * 1024;
  unsigned short* xb   = (unsigned short*)(ws);
  unsigned short* Wqt  = (unsigned short*)(ws + 16 * MB);
  unsigned short* Wkvt = (unsigned short*)(ws + 24 * MB);
  unsigned short* Wot  = (unsigned short*)(ws + 28 * MB);
  unsigned short* qb   = (unsigned short*)(ws + 36 * MB);
  unsigned short* kvb  = (unsigned short*)(ws + 52 * MB);
  unsigned short* attn = (unsigned short*)(ws + 60 * MB);

  const int M = BDIM * SLEN;  // 4096
  dim3 blk(256);

  cast_f32_bf16<<<(M * 2048) / (256 * 8), blk, 0, stream>>>(x, xb);
  transpose_cast<<<dim3(64, 64), blk, 0, stream>>>(Wq, Wqt, 2048, 2048);
  transpose_cast<<<dim3(16, 64), blk, 0, stream>>>(Wk, Wkvt, 2048, 512);
  transpose_cast<<<dim3(16, 64), blk, 0, stream>>>(
      Wv, Wkvt + (size_t)512 * 2048, 2048, 512);
  transpose_cast<<<dim3(64, 64), blk, 0, stream>>>(Wo, Wot, 2048, 2048);

  gemm_mfma_bt<true><<<dim3(16, 32), blk, 0, stream>>>(xb, Wqt, qb, M, 2048, 2048);
  gemm_mfma_bt<true><<<dim3(8, 32), blk, 0, stream>>>(xb, Wkvt, kvb, M, 1024, 2048);

  rope_xpos_ip<<<(M * NH * 64) / 256, blk, 0, stream>>>(
      qb, 2048, 4, 0, 0.088388347648318447f);
  rope_xpos_ip<<<(M * NKV * 64) / 256, blk, 0, stream>>>(kvb, 1024, 2, 1, 1.0f);

  flash_attn_v3<<<BDIM * NH * (SLEN / 64), blk, 0, stream>>>(qb, kvb, attn);

  gemm_mfma_bt<false><<<dim3(16, 32), blk, 0, stream>>>(attn, Wot, out, M, 2048, 2048);
}